// Round 8
// baseline (446.333 us; speedup 1.0000x reference)
//
#include <hip/hip_runtime.h>

typedef __bf16 bf16x8 __attribute__((ext_vector_type(8)));
typedef float f32x16 __attribute__((ext_vector_type(16)));

__device__ __forceinline__ unsigned short f2bf(float f) {
    union { float f; unsigned u; } v; v.f = f;
    unsigned r = (v.u + 0x7FFFu + ((v.u >> 16) & 1u)) >> 16;
    return (unsigned short)r;
}
// pack two f32 -> one u32 of 2x bf16 (RNE; compiler fuses to v_cvt_pk_bf16_f32)
__device__ __forceinline__ unsigned pk2(float lo, float hi) {
    union { unsigned u; __bf16 h[2]; } t;
    t.h[0] = (__bf16)lo; t.h[1] = (__bf16)hi; return t.u;
}

// ---- weight conversion into MFMA fragment order (32x32x16 bf16) ----
// Frag mapping: lane l holds W[k0 + (l>>5)*8 + j][n0 + (l&31)], j=0..7.
// W1F index = ((g*8 + kb)*64 + l)*8 + j   (g: hidden col-group 0..31, kb: K-step 0..7, K pad 119->128)
// W2F index = ((gn*64 + kb)*64 + l)*8 + j (gn: out col-group 0..7, kb: K-step 0..63)
__global__ void conv_w(const float* __restrict__ W1, const float* __restrict__ W2,
                       unsigned short* __restrict__ W1F, unsigned short* __restrict__ W2F) {
    int b = blockIdx.x;
    if (b < 512) {
        int idx = b * 256 + threadIdx.x;                   // 131072
        int j = idx & 7, l = (idx >> 3) & 63, kb = (idx >> 9) & 7, g = idx >> 12;
        int k = kb * 16 + (l >> 5) * 8 + j;
        int h = g * 32 + (l & 31);
        float v = (k < 119) ? W1[(size_t)k * 1024 + h] : 0.0f;
        W1F[idx] = f2bf(v);
    } else {
        int idx = (b - 512) * 256 + threadIdx.x;           // 262144
        int j = idx & 7, l = (idx >> 3) & 63, kb = (idx >> 9) & 63, gn = idx >> 15;
        int k = kb * 16 + (l >> 5) * 8 + j;
        int n = gn * 32 + (l & 31);
        W2F[idx] = f2bf(W2[(size_t)k * 256 + n]);
    }
}

// ---- fused features + MLP: BARRIER-FREE independent waves ----
// 256 threads (4 waves), 128 rows/block, grid 1024. Each wave owns 32 rows end-to-end:
//   for each hidden col-group gg (32 of them):
//     h = sum_ks mfma(W1frag[gg,ks], Xfrag[ks])        (8 MFMA, X in registers)
//     relu+bias, pack to bf16, lane^32 swap -> f0,f1 = phase-B A-frags for kc {2gg,2gg+1}
//     acc[ni] += mfma(f0, W2frag[kc0,ni]) + mfma(f1, W2frag[kc1,ni])   (16 MFMA)
// H never touches LDS; NO data barriers; per-wave VMEM/MFMA streams overlap freely.
// One raw s_barrier per chunk keeps the block's 4 identical-address waves convoyed
// so L1 (24 KB working set per g-step) serves the weight re-reads.
__global__ __launch_bounds__(256, 2) void mlp_fused(
    const float* __restrict__ hole, const float* __restrict__ board,
    const float* __restrict__ b1, const float* __restrict__ b2,
    const unsigned short* __restrict__ W1F, const unsigned short* __restrict__ W2F,
    float* __restrict__ out)
{
    __shared__ unsigned short Xsf[4][8][64][8];   // 32 KB frag-ordered X: [wave][ks][lane][j]

    const int tid  = threadIdx.x;
    const int w    = tid >> 6;
    const int lane = tid & 63;
    const int l32  = lane & 31;
    const int hi   = lane >> 5;      // 0/1 half-wave
    const long r0  = (long)blockIdx.x * 128;

    // ---------------- feature extraction: thread t < 128 handles row r0+t ----------------
    if (tid < 128) {
        const long r = r0 + tid;
        const float4* hp = (const float4*)(hole + r * 52);
        const float4* bp = (const float4*)(board + r * 52);
        unsigned long long hm = 0ull, bm = 0ull;
        #pragma unroll
        for (int i = 0; i < 13; ++i) {
            float4 h4 = hp[i], b4 = bp[i];
            int base = i * 4;
            hm |= ((unsigned long long)(h4.x > 0.5f)) << (base + 0);
            hm |= ((unsigned long long)(h4.y > 0.5f)) << (base + 1);
            hm |= ((unsigned long long)(h4.z > 0.5f)) << (base + 2);
            hm |= ((unsigned long long)(h4.w > 0.5f)) << (base + 3);
            bm |= ((unsigned long long)(b4.x > 0.5f)) << (base + 0);
            bm |= ((unsigned long long)(b4.y > 0.5f)) << (base + 1);
            bm |= ((unsigned long long)(b4.z > 0.5f)) << (base + 2);
            bm |= ((unsigned long long)(b4.w > 0.5f)) << (base + 3);
        }
        const unsigned long long am = hm | bm;
        const int bcount = __popcll(bm);
        const int hcount = __popcll(hm);

        int pairs_b = 0, pairs_a = 0;
        bool trips_b = false, trips_a = false;
        unsigned prb = 0, pra = 0;
        #pragma unroll
        for (int rr = 0; rr < 13; ++rr) {
            int cb = __popc((unsigned)((bm >> (4 * rr)) & 0xFull));
            int ca = __popc((unsigned)((am >> (4 * rr)) & 0xFull));
            pairs_b += (cb >= 2); trips_b = trips_b || (cb >= 3); prb |= (unsigned)(cb > 0) << rr;
            pairs_a += (ca >= 2); trips_a = trips_a || (ca >= 3); pra |= (unsigned)(ca > 0) << rr;
        }
        const unsigned long long SM = 0x1111111111111ull;
        int bscm = 0, ascm = 0;
        #pragma unroll
        for (int s = 0; s < 4; ++s) {
            int bs = __popcll(bm & (SM << s));
            int as = __popcll(am & (SM << s));
            bscm = bs > bscm ? bs : bscm;
            ascm = as > ascm ? as : ascm;
        }
        float strength = trips_b ? 0.8f : (pairs_b >= 2 ? 0.6f : (pairs_b >= 1 ? 0.4f : 0.2f));
        if (bcount == 0) strength = 0.0f;
        float flush_b = (bscm >= 3 && bcount > 0) ? 1.0f : 0.0f;
        bool sb = false;
        #pragma unroll
        for (int i = 0; i < 13; ++i) sb = sb || (__popc((prb >> i) & 0x1Fu) >= 3);
        float straight_b = (sb && bcount > 0) ? 1.0f : 0.0f;
        float gr0 = (bcount == 0) ? 1.0f : 0.0f;
        float gr3 = (bcount == 3) ? 1.0f : 0.0f;
        float gr4 = (bcount == 4) ? 1.0f : 0.0f;
        float gr5 = (bcount == 5) ? 1.0f : 0.0f;
        float valid = (hcount >= 2 && bcount >= 1) ? 1.0f : 0.0f;
        float flush_draw = (ascm == 4) ? 1.0f : 0.0f;
        float flush_outs = fmaxf(0.0f, 13.0f - (float)ascm) * (1.0f / 13.0f);
        int first = -1;
        #pragma unroll
        for (int i = 0; i < 13; ++i) {
            bool qq = (((pra >> i) & 1u) != 0u) && (__popc((pra >> i) & 0x1Fu) >= 4);
            if (qq && first < 0) first = i;
        }
        float straight_draw = (first >= 0) ? 1.0f : 0.0f;
        float straight_outs = 0.0f;
        if (first >= 0) {
            int c4 = __popc((pra >> first) & 0xFu);
            straight_outs = (c4 >= 4) ? 0.4f : 0.2f;
        }
        float total_outs = flush_draw * flush_outs * 9.0f + straight_draw * straight_outs * 8.0f;
        float remaining = 52.0f - (float)(hcount + bcount);
        float equity = 0.0f;
        if (remaining > 0.0f) equity = fminf(1.0f, total_outs / fmaxf(remaining, 1.0f));
        float hit_pair  = (pairs_a >= 1) ? 1.0f : 0.0f;
        float hit_trips = trips_a ? 1.0f : 0.0f;
        float hit_two   = (pairs_a >= 2) ? 1.0f : 0.0f;

        float feats[15] = { strength, flush_b, straight_b, gr0, gr3, gr4, gr5,
                            valid * flush_draw, valid * flush_outs, valid * straight_draw,
                            valid * straight_outs, valid * equity,
                            valid * hit_pair, valid * hit_trips, valid * hit_two };
        unsigned short xv[128];
        #pragma unroll
        for (int i = 0; i < 52; ++i) xv[i]      = ((hm >> i) & 1ull) ? (unsigned short)0x3F80 : (unsigned short)0;
        #pragma unroll
        for (int i = 0; i < 52; ++i) xv[52 + i] = ((bm >> i) & 1ull) ? (unsigned short)0x3F80 : (unsigned short)0;
        #pragma unroll
        for (int i = 0; i < 15; ++i) xv[104 + i] = f2bf(feats[i]);
        #pragma unroll
        for (int i = 119; i < 128; ++i) xv[i] = 0;

        // scatter row into frag order: B-frag lane (r&31)+32*h2 holds X[k=ks*16+h2*8+j]
        const int rw = tid >> 5, lr = tid & 31;
        #pragma unroll
        for (int ks = 0; ks < 8; ++ks)
            #pragma unroll
            for (int h2 = 0; h2 < 2; ++h2) {
                const int kb = ks * 16 + h2 * 8;
                uint4 v;
                v.x = (unsigned)xv[kb + 0] | ((unsigned)xv[kb + 1] << 16);
                v.y = (unsigned)xv[kb + 2] | ((unsigned)xv[kb + 3] << 16);
                v.z = (unsigned)xv[kb + 4] | ((unsigned)xv[kb + 5] << 16);
                v.w = (unsigned)xv[kb + 6] | ((unsigned)xv[kb + 7] << 16);
                *(uint4*)&Xsf[rw][ks][lr + 32 * h2][0] = v;
            }
    }

    __syncthreads();   // Xsf visible -- the ONLY full barrier

    // ---- X fragments -> registers (lane-linear b128, conflict-free), LDS done ----
    bf16x8 xf[8];
    #pragma unroll
    for (int ks = 0; ks < 8; ++ks) xf[ks] = *(const bf16x8*)&Xsf[w][ks][lane][0];

    f32x16 acc[8];
    #pragma unroll
    for (int ni = 0; ni < 8; ++ni)
        #pragma unroll
        for (int r = 0; r < 16; ++r) acc[ni][r] = 0.0f;

    // ---- main loop: fully register-resident per wave; no data barriers ----
    for (int c = 0; c < 8; ++c) {
        #pragma unroll
        for (int g = 0; g < 4; ++g) {
            const int gg = c * 4 + g;                  // hidden col-group 0..31
            const unsigned short* w1p = W1F + (size_t)gg * 8 * 512 + lane * 8;

            // phase A: h = W1(:,gg-group)^T-frag x X-frag  (H^T: m in lane, h-col in regs)
            f32x16 h;
            #pragma unroll
            for (int r = 0; r < 16; ++r) h[r] = 0.0f;
            #pragma unroll
            for (int ks = 0; ks < 8; ++ks) {
                bf16x8 wfr = *(const bf16x8*)(w1p + ks * 512);
                h = __builtin_amdgcn_mfma_f32_32x32x16_bf16(wfr, xf[ks], h, 0, 0, 0);
            }

            // relu + bias, pack, lane^32 swap -> A-frags f0,f1 for kc {2gg, 2gg+1}
            float4 bq[4];
            #pragma unroll
            for (int q = 0; q < 4; ++q) bq[q] = *(const float4*)&b1[gg * 32 + q * 8 + 4 * hi];
            float v[16];
            #pragma unroll
            for (int q = 0; q < 4; ++q) {
                v[4 * q + 0] = fmaxf(h[4 * q + 0] + bq[q].x, 0.0f);
                v[4 * q + 1] = fmaxf(h[4 * q + 1] + bq[q].y, 0.0f);
                v[4 * q + 2] = fmaxf(h[4 * q + 2] + bq[q].z, 0.0f);
                v[4 * q + 3] = fmaxf(h[4 * q + 3] + bq[q].w, 0.0f);
            }
            unsigned p0 = pk2(v[0], v[1]),   p1 = pk2(v[2], v[3]);
            unsigned p2 = pk2(v[4], v[5]),   p3 = pk2(v[6], v[7]);
            unsigned p4 = pk2(v[8], v[9]),   p5 = pk2(v[10], v[11]);
            unsigned p6 = pk2(v[12], v[13]), p7 = pk2(v[14], v[15]);
            unsigned q0 = (unsigned)__shfl_xor((int)p0, 32, 64);
            unsigned q1 = (unsigned)__shfl_xor((int)p1, 32, 64);
            unsigned q2 = (unsigned)__shfl_xor((int)p2, 32, 64);
            unsigned q3 = (unsigned)__shfl_xor((int)p3, 32, 64);
            unsigned q4 = (unsigned)__shfl_xor((int)p4, 32, 64);
            unsigned q5 = (unsigned)__shfl_xor((int)p5, 32, 64);
            unsigned q6 = (unsigned)__shfl_xor((int)p6, 32, 64);
            unsigned q7 = (unsigned)__shfl_xor((int)p7, 32, 64);
            uint4 f0, f1;
            f0.x = hi ? q2 : p0;  f0.y = hi ? q3 : p1;  f0.z = hi ? p2 : q0;  f0.w = hi ? p3 : q1;
            f1.x = hi ? q6 : p4;  f1.y = hi ? q7 : p5;  f1.z = hi ? p6 : q4;  f1.w = hi ? p7 : q5;
            bf16x8 a0 = __builtin_bit_cast(bf16x8, f0);
            bf16x8 a1 = __builtin_bit_cast(bf16x8, f1);

            // phase B partial: acc[ni] += f0 x W2[kc0, ni] + f1 x W2[kc1, ni]
            const size_t kc0 = (size_t)gg * 2, kc1 = kc0 + 1;
            #pragma unroll
            for (int ni = 0; ni < 8; ++ni) {
                const unsigned short* w2p = W2F + ((size_t)ni * 64) * 512 + lane * 8;
                bf16x8 b0  = *(const bf16x8*)(w2p + kc0 * 512);
                bf16x8 b1f = *(const bf16x8*)(w2p + kc1 * 512);
                acc[ni] = __builtin_amdgcn_mfma_f32_32x32x16_bf16(a0, b0,  acc[ni], 0, 0, 0);
                acc[ni] = __builtin_amdgcn_mfma_f32_32x32x16_bf16(a1, b1f, acc[ni], 0, 0, 0);
            }
        }
        __builtin_amdgcn_s_barrier();   // raw convoy barrier (no waitcnt): keeps the 4 waves'
                                        // identical weight streams within one chunk for L1 reuse
    }

    // ---- epilogue: + b2, store f32 (wave w owns rows w*32..w*32+31) ----
    #pragma unroll
    for (int ni = 0; ni < 8; ++ni) {
        const int col = ni * 32 + l32;
        const float bb = b2[col];
        #pragma unroll
        for (int r = 0; r < 16; ++r) {
            const long row = r0 + w * 32 + (r & 3) + 8 * (r >> 2) + 4 * hi;
            out[row * 256 + col] = acc[ni][r] + bb;
        }
    }
}

extern "C" void kernel_launch(void* const* d_in, const int* in_sizes, int n_in,
                              void* d_out, int out_size, void* d_ws, size_t ws_size,
                              hipStream_t stream) {
    (void)in_sizes; (void)n_in; (void)out_size; (void)ws_size;
    const float* hole  = (const float*)d_in[0];
    const float* board = (const float*)d_in[1];
    const float* W1    = (const float*)d_in[2];
    const float* b1    = (const float*)d_in[3];
    const float* W2    = (const float*)d_in[4];
    const float* b2    = (const float*)d_in[5];
    float* out = (float*)d_out;

    unsigned short* W1F = (unsigned short*)d_ws;            // 131072 bf16 = 256 KB
    unsigned short* W2F = W1F + 131072;                     // 262144 bf16 = 512 KB

    conv_w<<<1536, 256, 0, stream>>>(W1, W2, W1F, W2F);
    mlp_fused<<<131072 / 128, 256, 0, stream>>>(hole, board, b1, b2, W1F, W2F, out);
}

// Round 10
// 327.752 us; speedup vs baseline: 1.3618x; 1.3618x over previous
//
#include <hip/hip_runtime.h>

typedef __bf16 bf16x8 __attribute__((ext_vector_type(8)));
typedef float f32x16 __attribute__((ext_vector_type(16)));

__device__ __forceinline__ unsigned short f2bf(float f) {
    union { float f; unsigned u; } v; v.f = f;
    unsigned r = (v.u + 0x7FFFu + ((v.u >> 16) & 1u)) >> 16;
    return (unsigned short)r;
}
// pack two f32 -> one u32 of 2x bf16 (RNE; compiler fuses to v_cvt_pk_bf16_f32)
__device__ __forceinline__ unsigned pk2(float lo, float hi) {
    union { unsigned u; __bf16 h[2]; } t;
    t.h[0] = (__bf16)lo; t.h[1] = (__bf16)hi; return t.u;
}

// ---- weight conversion into MFMA fragment order (32x32x16 bf16) ----
// Frag mapping: lane l holds W[k0 + (l>>5)*8 + j][n0 + (l&31)], j=0..7.
// W1F index = ((g*8 + kb)*64 + l)*8 + j   (g: hidden col-group 0..31, kb: K-step 0..7, K pad 119->128)
// W2F index = ((gn*64 + kb)*64 + l)*8 + j (gn: out col-group 0..7, kb: K-step 0..63)
__global__ void conv_w(const float* __restrict__ W1, const float* __restrict__ W2,
                       unsigned short* __restrict__ W1F, unsigned short* __restrict__ W2F) {
    int b = blockIdx.x;
    if (b < 512) {
        int idx = b * 256 + threadIdx.x;                   // 131072
        int j = idx & 7, l = (idx >> 3) & 63, kb = (idx >> 9) & 7, g = idx >> 12;
        int k = kb * 16 + (l >> 5) * 8 + j;
        int h = g * 32 + (l & 31);
        float v = (k < 119) ? W1[(size_t)k * 1024 + h] : 0.0f;
        W1F[idx] = f2bf(v);
    } else {
        int idx = (b - 512) * 256 + threadIdx.x;           // 262144
        int j = idx & 7, l = (idx >> 3) & 63, kb = (idx >> 9) & 63, gn = idx >> 15;
        int k = kb * 16 + (l >> 5) * 8 + j;
        int n = gn * 32 + (l & 31);
        W2F[idx] = f2bf(W2[(size_t)k * 256 + n]);
    }
}

// ---- fused features + MLP: 128 rows/block, 8 waves, m-half specialization ----
// grid 1024 x 512 threads. Wave w: mh = w>>2 (m-half: m-tiles {2mh,2mh+1}), np = w&3.
// Phase A (chunk c): wave computes hg = c*4+np for BOTH its m-tiles (X frags in REGISTERS),
//   packswap -> H A-frags for kc {2np,2np+1} -> 4 lane-linear b128 LDS writes.
// Phase B (chunk c): wave owns n-groups {2np,2np+1} x its 2 m-tiles: 16 lane-linear H reads,
//   16 W2 loads, 32 MFMA into acc[2][2] (64 VGPR).
// X staging ALIASES H buffer 0: after prologue clobbers it, the compiler cannot re-read
// X from LDS (the R2 remat failure) -- the 64 X VGPRs must stay resident.
// Weights per block 768 KB over 128 rows (2x better L2 amortization than 64-row blocks).
// Compiler-scheduled loads; ONE lgkm-fence + s_barrier per chunk (vmcnt never drained).
__global__ __launch_bounds__(512, 2) void mlp_fused(
    const float* __restrict__ hole, const float* __restrict__ board,
    const float* __restrict__ b1, const float* __restrict__ b2,
    const unsigned short* __restrict__ W1F, const unsigned short* __restrict__ W2F,
    float* __restrict__ out)
{
    // H double-buffer, frag-ordered: HsF[buf][mi][kc][lane][j]. 64 KB.
    // Buffer 0 doubles as the X staging area during init (X frag scatter, same layout).
    __shared__ unsigned short HsF[2][4][8][64][8];

    const int tid  = threadIdx.x;
    const int w    = tid >> 6;       // 0..7
    const int mh   = w >> 2;         // m-half: m-tiles {2mh, 2mh+1}
    const int np   = w & 3;          // hg-local (phase A) / n-pair (phase B)
    const int lane = tid & 63;
    const int l32  = lane & 31;
    const int hi   = lane >> 5;      // 0/1 half-wave
    const long r0  = (long)blockIdx.x * 128;
    const int crot = (int)((blockIdx.x + (blockIdx.x >> 7)) & 7);

    // ---------------- feature extraction: thread t < 128 handles row r0+t ----------------
    if (tid < 128) {
        const long r = r0 + tid;
        const float4* hp = (const float4*)(hole + r * 52);
        const float4* bp = (const float4*)(board + r * 52);
        unsigned long long hm = 0ull, bm = 0ull;
        #pragma unroll
        for (int i = 0; i < 13; ++i) {
            float4 h4 = hp[i], b4 = bp[i];
            int base = i * 4;
            hm |= ((unsigned long long)(h4.x > 0.5f)) << (base + 0);
            hm |= ((unsigned long long)(h4.y > 0.5f)) << (base + 1);
            hm |= ((unsigned long long)(h4.z > 0.5f)) << (base + 2);
            hm |= ((unsigned long long)(h4.w > 0.5f)) << (base + 3);
            bm |= ((unsigned long long)(b4.x > 0.5f)) << (base + 0);
            bm |= ((unsigned long long)(b4.y > 0.5f)) << (base + 1);
            bm |= ((unsigned long long)(b4.z > 0.5f)) << (base + 2);
            bm |= ((unsigned long long)(b4.w > 0.5f)) << (base + 3);
        }
        const unsigned long long am = hm | bm;
        const int bcount = __popcll(bm);
        const int hcount = __popcll(hm);

        int pairs_b = 0, pairs_a = 0;
        bool trips_b = false, trips_a = false;
        unsigned prb = 0, pra = 0;
        #pragma unroll
        for (int rr = 0; rr < 13; ++rr) {
            int cb = __popc((unsigned)((bm >> (4 * rr)) & 0xFull));
            int ca = __popc((unsigned)((am >> (4 * rr)) & 0xFull));
            pairs_b += (cb >= 2); trips_b = trips_b || (cb >= 3); prb |= (unsigned)(cb > 0) << rr;
            pairs_a += (ca >= 2); trips_a = trips_a || (ca >= 3); pra |= (unsigned)(ca > 0) << rr;
        }
        const unsigned long long SM = 0x1111111111111ull;
        int bscm = 0, ascm = 0;
        #pragma unroll
        for (int s = 0; s < 4; ++s) {
            int bs = __popcll(bm & (SM << s));
            int as = __popcll(am & (SM << s));
            bscm = bs > bscm ? bs : bscm;
            ascm = as > ascm ? as : ascm;
        }
        float strength = trips_b ? 0.8f : (pairs_b >= 2 ? 0.6f : (pairs_b >= 1 ? 0.4f : 0.2f));
        if (bcount == 0) strength = 0.0f;
        float flush_b = (bscm >= 3 && bcount > 0) ? 1.0f : 0.0f;
        bool sb = false;
        #pragma unroll
        for (int i = 0; i < 13; ++i) sb = sb || (__popc((prb >> i) & 0x1Fu) >= 3);
        float straight_b = (sb && bcount > 0) ? 1.0f : 0.0f;
        float gr0 = (bcount == 0) ? 1.0f : 0.0f;
        float gr3 = (bcount == 3) ? 1.0f : 0.0f;
        float gr4 = (bcount == 4) ? 1.0f : 0.0f;
        float gr5 = (bcount == 5) ? 1.0f : 0.0f;
        float valid = (hcount >= 2 && bcount >= 1) ? 1.0f : 0.0f;
        float flush_draw = (ascm == 4) ? 1.0f : 0.0f;
        float flush_outs = fmaxf(0.0f, 13.0f - (float)ascm) * (1.0f / 13.0f);
        int first = -1;
        #pragma unroll
        for (int i = 0; i < 13; ++i) {
            bool qq = (((pra >> i) & 1u) != 0u) && (__popc((pra >> i) & 0x1Fu) >= 4);
            if (qq && first < 0) first = i;
        }
        float straight_draw = (first >= 0) ? 1.0f : 0.0f;
        float straight_outs = 0.0f;
        if (first >= 0) {
            int c4 = __popc((pra >> first) & 0xFu);
            straight_outs = (c4 >= 4) ? 0.4f : 0.2f;
        }
        float total_outs = flush_draw * flush_outs * 9.0f + straight_draw * straight_outs * 8.0f;
        float remaining = 52.0f - (float)(hcount + bcount);
        float equity = 0.0f;
        if (remaining > 0.0f) equity = fminf(1.0f, total_outs / fmaxf(remaining, 1.0f));
        float hit_pair  = (pairs_a >= 1) ? 1.0f : 0.0f;
        float hit_trips = trips_a ? 1.0f : 0.0f;
        float hit_two   = (pairs_a >= 2) ? 1.0f : 0.0f;

        float feats[15] = { strength, flush_b, straight_b, gr0, gr3, gr4, gr5,
                            valid * flush_draw, valid * flush_outs, valid * straight_draw,
                            valid * straight_outs, valid * equity,
                            valid * hit_pair, valid * hit_trips, valid * hit_two };
        unsigned short xv[128];
        #pragma unroll
        for (int i = 0; i < 52; ++i) xv[i]      = ((hm >> i) & 1ull) ? (unsigned short)0x3F80 : (unsigned short)0;
        #pragma unroll
        for (int i = 0; i < 52; ++i) xv[52 + i] = ((bm >> i) & 1ull) ? (unsigned short)0x3F80 : (unsigned short)0;
        #pragma unroll
        for (int i = 0; i < 15; ++i) xv[104 + i] = f2bf(feats[i]);
        #pragma unroll
        for (int i = 119; i < 128; ++i) xv[i] = 0;

        // scatter row into B-frag order (proven conflict-free in R8):
        // X frag for m-tile mi: lane lr+32*h2 holds X[mi*32+lr][ks*16+h2*8+j]
        const int rw = tid >> 5, lr = tid & 31;
        #pragma unroll
        for (int ks = 0; ks < 8; ++ks)
            #pragma unroll
            for (int h2 = 0; h2 < 2; ++h2) {
                const int kb = ks * 16 + h2 * 8;
                uint4 v;
                v.x = (unsigned)xv[kb + 0] | ((unsigned)xv[kb + 1] << 16);
                v.y = (unsigned)xv[kb + 2] | ((unsigned)xv[kb + 3] << 16);
                v.z = (unsigned)xv[kb + 4] | ((unsigned)xv[kb + 5] << 16);
                v.w = (unsigned)xv[kb + 6] | ((unsigned)xv[kb + 7] << 16);
                *(uint4*)&HsF[0][rw][ks][lr + 32 * h2][0] = v;   // X staging aliases H buf 0
            }
    }

    __syncthreads();   // X scatter visible

    // ---- X fragments -> registers, once. Lane-linear b128 (conflict-free). ----
    // After the next barrier, phase A clobbers this LDS region -> compiler must keep these regs.
    bf16x8 xf[2][8];
    #pragma unroll
    for (int di = 0; di < 2; ++di)
        #pragma unroll
        for (int ks = 0; ks < 8; ++ks)
            xf[di][ks] = *(const bf16x8*)&HsF[0][mh * 2 + di][ks][lane][0];

    __syncthreads();   // all X reads done; buf 0 free for H

    f32x16 acc[2][2];
    #pragma unroll
    for (int a = 0; a < 2; ++a)
        #pragma unroll
        for (int b = 0; b < 2; ++b)
            #pragma unroll
            for (int r = 0; r < 16; ++r) acc[a][b][r] = 0.0f;

    // ---- phase A body: chunk cn -> HsF[buf] ----
    auto phaseA = [&](int cn, int buf) {
        const int hg = cn * 4 + np;
        const unsigned short* w1p = W1F + ((size_t)hg * 8) * 512 + lane * 8;
        float4 bq[4];
        #pragma unroll
        for (int q = 0; q < 4; ++q) bq[q] = *(const float4*)&b1[hg * 32 + q * 8 + 4 * hi];
        #pragma unroll
        for (int di = 0; di < 2; ++di) {
            f32x16 h;
            #pragma unroll
            for (int r = 0; r < 16; ++r) h[r] = 0.0f;
            #pragma unroll
            for (int ks = 0; ks < 8; ++ks) {
                bf16x8 wfr = *(const bf16x8*)(w1p + ks * 512);
                h = __builtin_amdgcn_mfma_f32_32x32x16_bf16(wfr, xf[di][ks], h, 0, 0, 0);
            }
            // relu+bias, pack, lane^32 swap -> A-frags for kc {2np, 2np+1}
            float v[16];
            #pragma unroll
            for (int q = 0; q < 4; ++q) {
                v[4 * q + 0] = fmaxf(h[4 * q + 0] + bq[q].x, 0.0f);
                v[4 * q + 1] = fmaxf(h[4 * q + 1] + bq[q].y, 0.0f);
                v[4 * q + 2] = fmaxf(h[4 * q + 2] + bq[q].z, 0.0f);
                v[4 * q + 3] = fmaxf(h[4 * q + 3] + bq[q].w, 0.0f);
            }
            unsigned p0 = pk2(v[0], v[1]),   p1 = pk2(v[2], v[3]);
            unsigned p2 = pk2(v[4], v[5]),   p3 = pk2(v[6], v[7]);
            unsigned p4 = pk2(v[8], v[9]),   p5 = pk2(v[10], v[11]);
            unsigned p6 = pk2(v[12], v[13]), p7 = pk2(v[14], v[15]);
            unsigned q0 = (unsigned)__shfl_xor((int)p0, 32, 64);
            unsigned q1 = (unsigned)__shfl_xor((int)p1, 32, 64);
            unsigned q2 = (unsigned)__shfl_xor((int)p2, 32, 64);
            unsigned q3 = (unsigned)__shfl_xor((int)p3, 32, 64);
            unsigned q4 = (unsigned)__shfl_xor((int)p4, 32, 64);
            unsigned q5 = (unsigned)__shfl_xor((int)p5, 32, 64);
            unsigned q6 = (unsigned)__shfl_xor((int)p6, 32, 64);
            unsigned q7 = (unsigned)__shfl_xor((int)p7, 32, 64);
            uint4 f0, f1;
            f0.x = hi ? q2 : p0;  f0.y = hi ? q3 : p1;  f0.z = hi ? p2 : q0;  f0.w = hi ? p3 : q1;
            f1.x = hi ? q6 : p4;  f1.y = hi ? q7 : p5;  f1.z = hi ? p6 : q4;  f1.w = hi ? p7 : q5;
            *(uint4*)&HsF[buf][mh * 2 + di][2 * np + 0][lane][0] = f0;
            *(uint4*)&HsF[buf][mh * 2 + di][2 * np + 1][lane][0] = f1;
        }
    };

    // ---- prologue: phase A chunk crot -> buf 0 (clobbers X staging) ----
    phaseA(crot, 0);
    asm volatile("s_waitcnt lgkmcnt(0)" ::: "memory");
    __builtin_amdgcn_s_barrier();

    // ---- main loop: one barrier per chunk ----
    for (int i = 0; i < 8; ++i) {
        const int cc  = (crot + i) & 7;
        const int buf = i & 1;

        // phase B, chunk cc: wave (mh, np) -> acc[di][ni]
        const unsigned short* w2p0 = W2F + ((size_t)((2 * np + 0) * 64 + cc * 8)) * 512 + lane * 8;
        const unsigned short* w2p1 = W2F + ((size_t)((2 * np + 1) * 64 + cc * 8)) * 512 + lane * 8;
        #pragma unroll
        for (int kc = 0; kc < 8; ++kc) {
            bf16x8 a0  = *(const bf16x8*)&HsF[buf][mh * 2 + 0][kc][lane][0];
            bf16x8 a1  = *(const bf16x8*)&HsF[buf][mh * 2 + 1][kc][lane][0];
            bf16x8 b0  = *(const bf16x8*)(w2p0 + kc * 512);
            bf16x8 b1f = *(const bf16x8*)(w2p1 + kc * 512);
            acc[0][0] = __builtin_amdgcn_mfma_f32_32x32x16_bf16(a0, b0,  acc[0][0], 0, 0, 0);
            acc[0][1] = __builtin_amdgcn_mfma_f32_32x32x16_bf16(a0, b1f, acc[0][1], 0, 0, 0);
            acc[1][0] = __builtin_amdgcn_mfma_f32_32x32x16_bf16(a1, b0,  acc[1][0], 0, 0, 0);
            acc[1][1] = __builtin_amdgcn_mfma_f32_32x32x16_bf16(a1, b1f, acc[1][1], 0, 0, 0);
        }

        if (i < 7) {
            // phase A, chunk cc+1 -> other buffer (its prior readers synced at end of i-1)
            phaseA((crot + i + 1) & 7, buf ^ 1);
            asm volatile("s_waitcnt lgkmcnt(0)" ::: "memory");   // my ds reads+writes retired
            __builtin_amdgcn_s_barrier();                        // vmcnt NOT drained
        }
    }

    // ---- epilogue: + b2, store f32 ----
    #pragma unroll
    for (int ni = 0; ni < 2; ++ni) {
        const int col = (2 * np + ni) * 32 + l32;
        const float bb = b2[col];
        #pragma unroll
        for (int di = 0; di < 2; ++di) {
            #pragma unroll
            for (int r = 0; r < 16; ++r) {
                const long row = r0 + (mh * 2 + di) * 32 + (r & 3) + 8 * (r >> 2) + 4 * hi;
                out[row * 256 + col] = acc[di][ni][r] + bb;
            }
        }
    }
}

extern "C" void kernel_launch(void* const* d_in, const int* in_sizes, int n_in,
                              void* d_out, int out_size, void* d_ws, size_t ws_size,
                              hipStream_t stream) {
    (void)in_sizes; (void)n_in; (void)out_size; (void)ws_size;
    const float* hole  = (const float*)d_in[0];
    const float* board = (const float*)d_in[1];
    const float* W1    = (const float*)d_in[2];
    const float* b1    = (const float*)d_in[3];
    const float* W2    = (const float*)d_in[4];
    const float* b2    = (const float*)d_in[5];
    float* out = (float*)d_out;

    unsigned short* W1F = (unsigned short*)d_ws;            // 131072 bf16 = 256 KB
    unsigned short* W2F = W1F + 131072;                     // 262144 bf16 = 512 KB

    conv_w<<<1536, 256, 0, stream>>>(W1, W2, W1F, W2F);
    mlp_fused<<<131072 / 128, 512, 0, stream>>>(hole, board, b1, b2, W1F, W2F, out);
}

// Round 11
// 259.678 us; speedup vs baseline: 1.7188x; 1.2621x over previous
//
#include <hip/hip_runtime.h>

typedef __bf16 bf16x8 __attribute__((ext_vector_type(8)));
typedef __bf16 bf16x4 __attribute__((ext_vector_type(4)));
typedef float f32x16 __attribute__((ext_vector_type(16)));

__device__ __forceinline__ unsigned short f2bf(float f) {
    union { float f; unsigned u; } v; v.f = f;
    unsigned r = (v.u + 0x7FFFu + ((v.u >> 16) & 1u)) >> 16;
    return (unsigned short)r;
}

// ---- weight conversion into MFMA fragment order (32x32x16 bf16) ----
// Target layout (unchanged): W1F[((g*8+kb)*64+l)*8+j] = W1[k][h], k = kb*16+(l>>5)*8+j,
// h = g*32+(l&31) (k pad 119->128 with 0); W2F[((gn*64+kb)*64+l)*8+j] = W2[k][n] likewise.
// R11: iterate over the SOURCE layout -> fully coalesced float4 reads (the old version read
// at stride 4KB/1KB, one element per cacheline -> latency + 16x fetch amplification).
// Writes are scattered u16 stride-16B: fire-and-forget, merged in L2 by byte enables.
__global__ void conv_w(const float* __restrict__ W1, const float* __restrict__ W2,
                       unsigned short* __restrict__ W1F, unsigned short* __restrict__ W2F) {
    const int t = blockIdx.x * 256 + threadIdx.x;
    if (blockIdx.x < 128) {
        // W1 region: t in [0, 32768); 4 consecutive h per thread; idx = k*1024 + h
        const int idx = t * 4;
        const int k = idx >> 10, h = idx & 1023;
        float4 v;
        if (k < 119) v = *(const float4*)&W1[idx];
        else         v = make_float4(0.0f, 0.0f, 0.0f, 0.0f);   // pad rows 119..127
        const int kb = k >> 4, j = k & 7, hi5 = (k >> 3) & 1;
        const int g = h >> 5, l0 = hi5 * 32 + (h & 31);
        unsigned short* dst = W1F + ((size_t)(g * 8 + kb) * 64 + l0) * 8 + j;
        dst[0]  = f2bf(v.x);
        dst[8]  = f2bf(v.y);
        dst[16] = f2bf(v.z);
        dst[24] = f2bf(v.w);
    } else {
        // W2 region: t2 in [0, 65536); idx = k*256 + n
        const int t2 = t - 32768;
        const int idx = t2 * 4;
        const int k = idx >> 8, n = idx & 255;
        const float4 v = *(const float4*)&W2[idx];
        const int kb = k >> 4, j = k & 7, hi5 = (k >> 3) & 1;
        const int gn = n >> 5, l0 = hi5 * 32 + (n & 31);
        unsigned short* dst = W2F + ((size_t)(gn * 64 + kb) * 64 + l0) * 8 + j;
        dst[0]  = f2bf(v.x);
        dst[8]  = f2bf(v.y);
        dst[16] = f2bf(v.z);
        dst[24] = f2bf(v.w);
    }
}

// ---- fused features + MLP (R2 verbatim -- session best, 137 us) ----
// 256 threads (4 waves), 64 rows/block, grid 2048. chunk = 128 hidden cols (8 chunks).
// LDS layout (T2): element (r,c) at short-index r*128 + (c ^ ((r&7)<<3)).
// Pipeline: double-buffered Hs -> ONE barrier per chunk. W2F(c+1) prefetch issues after its
// last use and stays in flight across the barrier (vmcnt never drained at barriers).
__global__ __launch_bounds__(256, 2) void mlp_fused(
    const float* __restrict__ hole, const float* __restrict__ board,
    const float* __restrict__ b1, const float* __restrict__ b2,
    const unsigned short* __restrict__ W1F, const unsigned short* __restrict__ W2F,
    float* __restrict__ out)
{
    __shared__ unsigned short Xs[64 * 128];       // 16 KB, swizzled
    __shared__ unsigned short Hs[2][64 * 128];    // 2 x 16 KB, swizzled

    const int tid  = threadIdx.x;
    const int w    = tid >> 6;
    const int lane = tid & 63;
    const int l32  = lane & 31;
    const int hi   = lane >> 5;      // 0/1 half-wave
    const long r0  = (long)blockIdx.x * 64;

    // ---------------- feature extraction: thread t < 64 handles row r0+t ----------------
    if (tid < 64) {
        const long r = r0 + tid;
        const float4* hp = (const float4*)(hole + r * 52);
        const float4* bp = (const float4*)(board + r * 52);
        unsigned long long hm = 0ull, bm = 0ull;
        #pragma unroll
        for (int i = 0; i < 13; ++i) {
            float4 h4 = hp[i], b4 = bp[i];
            int base = i * 4;
            hm |= ((unsigned long long)(h4.x > 0.5f)) << (base + 0);
            hm |= ((unsigned long long)(h4.y > 0.5f)) << (base + 1);
            hm |= ((unsigned long long)(h4.z > 0.5f)) << (base + 2);
            hm |= ((unsigned long long)(h4.w > 0.5f)) << (base + 3);
            bm |= ((unsigned long long)(b4.x > 0.5f)) << (base + 0);
            bm |= ((unsigned long long)(b4.y > 0.5f)) << (base + 1);
            bm |= ((unsigned long long)(b4.z > 0.5f)) << (base + 2);
            bm |= ((unsigned long long)(b4.w > 0.5f)) << (base + 3);
        }
        const unsigned long long am = hm | bm;
        const int bcount = __popcll(bm);
        const int hcount = __popcll(hm);

        int pairs_b = 0, pairs_a = 0;
        bool trips_b = false, trips_a = false;
        unsigned prb = 0, pra = 0;
        #pragma unroll
        for (int rr = 0; rr < 13; ++rr) {
            int cb = __popc((unsigned)((bm >> (4 * rr)) & 0xFull));
            int ca = __popc((unsigned)((am >> (4 * rr)) & 0xFull));
            pairs_b += (cb >= 2); trips_b = trips_b || (cb >= 3); prb |= (unsigned)(cb > 0) << rr;
            pairs_a += (ca >= 2); trips_a = trips_a || (ca >= 3); pra |= (unsigned)(ca > 0) << rr;
        }
        const unsigned long long SM = 0x1111111111111ull;
        int bscm = 0, ascm = 0;
        #pragma unroll
        for (int s = 0; s < 4; ++s) {
            int bs = __popcll(bm & (SM << s));
            int as = __popcll(am & (SM << s));
            bscm = bs > bscm ? bs : bscm;
            ascm = as > ascm ? as : ascm;
        }
        float strength = trips_b ? 0.8f : (pairs_b >= 2 ? 0.6f : (pairs_b >= 1 ? 0.4f : 0.2f));
        if (bcount == 0) strength = 0.0f;
        float flush_b = (bscm >= 3 && bcount > 0) ? 1.0f : 0.0f;
        bool sb = false;
        #pragma unroll
        for (int i = 0; i < 13; ++i) sb = sb || (__popc((prb >> i) & 0x1Fu) >= 3);
        float straight_b = (sb && bcount > 0) ? 1.0f : 0.0f;
        float gr0 = (bcount == 0) ? 1.0f : 0.0f;
        float gr3 = (bcount == 3) ? 1.0f : 0.0f;
        float gr4 = (bcount == 4) ? 1.0f : 0.0f;
        float gr5 = (bcount == 5) ? 1.0f : 0.0f;
        float valid = (hcount >= 2 && bcount >= 1) ? 1.0f : 0.0f;
        float flush_draw = (ascm == 4) ? 1.0f : 0.0f;
        float flush_outs = fmaxf(0.0f, 13.0f - (float)ascm) * (1.0f / 13.0f);
        int first = -1;
        #pragma unroll
        for (int i = 0; i < 13; ++i) {
            bool qq = (((pra >> i) & 1u) != 0u) && (__popc((pra >> i) & 0x1Fu) >= 4);
            if (qq && first < 0) first = i;
        }
        float straight_draw = (first >= 0) ? 1.0f : 0.0f;
        float straight_outs = 0.0f;
        if (first >= 0) {
            int c4 = __popc((pra >> first) & 0xFu);
            straight_outs = (c4 >= 4) ? 0.4f : 0.2f;
        }
        float total_outs = flush_draw * flush_outs * 9.0f + straight_draw * straight_outs * 8.0f;
        float remaining = 52.0f - (float)(hcount + bcount);
        float equity = 0.0f;
        if (remaining > 0.0f) equity = fminf(1.0f, total_outs / fmaxf(remaining, 1.0f));
        float hit_pair  = (pairs_a >= 1) ? 1.0f : 0.0f;
        float hit_trips = trips_a ? 1.0f : 0.0f;
        float hit_two   = (pairs_a >= 2) ? 1.0f : 0.0f;

        unsigned short* xrow = &Xs[tid * 128];
        const int fsw = (tid & 7) << 3;          // swizzle constant for this row
        #pragma unroll
        for (int i = 0; i < 52; ++i) xrow[i ^ fsw]        = ((hm >> i) & 1ull) ? (unsigned short)0x3F80 : (unsigned short)0;
        #pragma unroll
        for (int i = 0; i < 52; ++i) xrow[(52 + i) ^ fsw] = ((bm >> i) & 1ull) ? (unsigned short)0x3F80 : (unsigned short)0;
        float feats[15] = { strength, flush_b, straight_b, gr0, gr3, gr4, gr5,
                            valid * flush_draw, valid * flush_outs, valid * straight_draw,
                            valid * straight_outs, valid * equity,
                            valid * hit_pair, valid * hit_trips, valid * hit_two };
        #pragma unroll
        for (int i = 0; i < 15; ++i) xrow[(104 + i) ^ fsw] = f2bf(feats[i]);
        #pragma unroll
        for (int i = 119; i < 128; ++i) xrow[i ^ fsw] = 0;
    }

    f32x16 acc[2][2];
    #pragma unroll
    for (int a = 0; a < 2; ++a)
        #pragma unroll
        for (int b = 0; b < 2; ++b)
            #pragma unroll
            for (int r = 0; r < 16; ++r) acc[a][b][r] = 0.0f;

    __syncthreads();

    const int sw = (l32 & 7) << 3;               // rows l32 and 32+l32 share (r&7)
    unsigned short* const x0 = &Xs[l32 * 128];
    unsigned short* const x1 = &Xs[(32 + l32) * 128];

    // ---- X fragments -> registers, once ----
    bf16x8 xf[2][8];
    #pragma unroll
    for (int ks = 0; ks < 8; ++ks) {
        const int off = (ks * 16 + hi * 8) ^ sw;
        xf[0][ks] = *(const bf16x8*)&x0[off];
        xf[1][ks] = *(const bf16x8*)&x1[off];
    }

    f32x16 h0, h1;
    bf16x8 wf1[8];
    bf16x8 wf20[8], wf21[8];
    float4 bq[4];

    // ---- prologue: phase A chunk 0 -> Hs[0]; W2F(0) prefetch; barrier ----
    {
        const unsigned short* w1p = W1F + ((size_t)(0 * 4 + w) * 8) * 512 + lane * 8;
        #pragma unroll
        for (int ks = 0; ks < 8; ++ks) wf1[ks] = *(const bf16x8*)(w1p + ks * 512);
        #pragma unroll
        for (int q = 0; q < 4; ++q) bq[q] = *(const float4*)&b1[0 * 128 + w * 32 + 8 * q + 4 * hi];
        #pragma unroll
        for (int r = 0; r < 16; ++r) { h0[r] = 0.0f; h1[r] = 0.0f; }
        #pragma unroll
        for (int ks = 0; ks < 8; ++ks) {
            h0 = __builtin_amdgcn_mfma_f32_32x32x16_bf16(wf1[ks], xf[0][ks], h0, 0, 0, 0);
            h1 = __builtin_amdgcn_mfma_f32_32x32x16_bf16(wf1[ks], xf[1][ks], h1, 0, 0, 0);
        }
        unsigned short* hr0 = &Hs[0][l32 * 128];
        unsigned short* hr1 = &Hs[0][(32 + l32) * 128];
        #pragma unroll
        for (int q = 0; q < 4; ++q) {
            const int cb = (w * 32 + 8 * q + 4 * hi) ^ sw;
            float f0 = fmaxf(h0[4 * q + 0] + bq[q].x, 0.0f);
            float f1 = fmaxf(h0[4 * q + 1] + bq[q].y, 0.0f);
            float f2 = fmaxf(h0[4 * q + 2] + bq[q].z, 0.0f);
            float f3 = fmaxf(h0[4 * q + 3] + bq[q].w, 0.0f);
            bf16x4 v = { (__bf16)f0, (__bf16)f1, (__bf16)f2, (__bf16)f3 };
            *(bf16x4*)&hr0[cb] = v;
            f0 = fmaxf(h1[4 * q + 0] + bq[q].x, 0.0f);
            f1 = fmaxf(h1[4 * q + 1] + bq[q].y, 0.0f);
            f2 = fmaxf(h1[4 * q + 2] + bq[q].z, 0.0f);
            f3 = fmaxf(h1[4 * q + 3] + bq[q].w, 0.0f);
            bf16x4 v2 = { (__bf16)f0, (__bf16)f1, (__bf16)f2, (__bf16)f3 };
            *(bf16x4*)&hr1[cb] = v2;
        }
        // W2F(0) prefetch: issued before barrier, in flight across it
        const unsigned short* w2p0 = W2F + ((size_t)(2 * w + 0) * 64 + 0 * 8) * 512 + lane * 8;
        const unsigned short* w2p1 = W2F + ((size_t)(2 * w + 1) * 64 + 0 * 8) * 512 + lane * 8;
        #pragma unroll
        for (int ks = 0; ks < 8; ++ks) {
            wf20[ks] = *(const bf16x8*)(w2p0 + ks * 512);
            wf21[ks] = *(const bf16x8*)(w2p1 + ks * 512);
        }
        asm volatile("s_waitcnt lgkmcnt(0)" ::: "memory");
        __builtin_amdgcn_s_barrier();
    }

    // ---- main loop: ONE barrier per chunk ----
    for (int c = 0; c < 8; ++c) {
        const unsigned short* hr0 = &Hs[c & 1][l32 * 128];
        const unsigned short* hr1 = &Hs[c & 1][(32 + l32) * 128];

        if (c < 7) {
            // issue W1F(c+1) + bias loads at region top: latency hides under phase-B MFMAs
            const unsigned short* w1p = W1F + ((size_t)((c + 1) * 4 + w) * 8) * 512 + lane * 8;
            #pragma unroll
            for (int ks = 0; ks < 8; ++ks) wf1[ks] = *(const bf16x8*)(w1p + ks * 512);
            #pragma unroll
            for (int q = 0; q < 4; ++q) bq[q] = *(const float4*)&b1[(c + 1) * 128 + w * 32 + 8 * q + 4 * hi];
        }

        // ---- phase B, chunk c ----
        #pragma unroll
        for (int ks = 0; ks < 8; ++ks) {
            const int off = (ks * 16 + hi * 8) ^ sw;
            bf16x8 a0 = *(const bf16x8*)&hr0[off];
            bf16x8 a1 = *(const bf16x8*)&hr1[off];
            acc[0][0] = __builtin_amdgcn_mfma_f32_32x32x16_bf16(a0, wf20[ks], acc[0][0], 0, 0, 0);
            acc[0][1] = __builtin_amdgcn_mfma_f32_32x32x16_bf16(a0, wf21[ks], acc[0][1], 0, 0, 0);
            acc[1][0] = __builtin_amdgcn_mfma_f32_32x32x16_bf16(a1, wf20[ks], acc[1][0], 0, 0, 0);
            acc[1][1] = __builtin_amdgcn_mfma_f32_32x32x16_bf16(a1, wf21[ks], acc[1][1], 0, 0, 0);
        }

        if (c < 7) {
            // W2F(c+1) prefetch: after last wf2 use, before barrier -> in flight across it
            const unsigned short* w2p0 = W2F + ((size_t)(2 * w + 0) * 64 + (c + 1) * 8) * 512 + lane * 8;
            const unsigned short* w2p1 = W2F + ((size_t)(2 * w + 1) * 64 + (c + 1) * 8) * 512 + lane * 8;
            #pragma unroll
            for (int ks = 0; ks < 8; ++ks) {
                wf20[ks] = *(const bf16x8*)(w2p0 + ks * 512);
                wf21[ks] = *(const bf16x8*)(w2p1 + ks * 512);
            }

            // ---- phase A, chunk c+1 (pure-register MFMA stream) ----
            #pragma unroll
            for (int r = 0; r < 16; ++r) { h0[r] = 0.0f; h1[r] = 0.0f; }
            #pragma unroll
            for (int ks = 0; ks < 8; ++ks) {
                h0 = __builtin_amdgcn_mfma_f32_32x32x16_bf16(wf1[ks], xf[0][ks], h0, 0, 0, 0);
                h1 = __builtin_amdgcn_mfma_f32_32x32x16_bf16(wf1[ks], xf[1][ks], h1, 0, 0, 0);
            }

            // ---- write H(c+1) -> Hs[(c+1)&1] ----
            unsigned short* hw0 = &Hs[(c + 1) & 1][l32 * 128];
            unsigned short* hw1 = &Hs[(c + 1) & 1][(32 + l32) * 128];
            #pragma unroll
            for (int q = 0; q < 4; ++q) {
                const int cb = (w * 32 + 8 * q + 4 * hi) ^ sw;
                float f0 = fmaxf(h0[4 * q + 0] + bq[q].x, 0.0f);
                float f1 = fmaxf(h0[4 * q + 1] + bq[q].y, 0.0f);
                float f2 = fmaxf(h0[4 * q + 2] + bq[q].z, 0.0f);
                float f3 = fmaxf(h0[4 * q + 3] + bq[q].w, 0.0f);
                bf16x4 v = { (__bf16)f0, (__bf16)f1, (__bf16)f2, (__bf16)f3 };
                *(bf16x4*)&hw0[cb] = v;
                f0 = fmaxf(h1[4 * q + 0] + bq[q].x, 0.0f);
                f1 = fmaxf(h1[4 * q + 1] + bq[q].y, 0.0f);
                f2 = fmaxf(h1[4 * q + 2] + bq[q].z, 0.0f);
                f3 = fmaxf(h1[4 * q + 3] + bq[q].w, 0.0f);
                bf16x4 v2 = { (__bf16)f0, (__bf16)f1, (__bf16)f2, (__bf16)f3 };
                *(bf16x4*)&hw1[cb] = v2;
            }

            asm volatile("s_waitcnt lgkmcnt(0)" ::: "memory");   // my ds reads+writes retired
            __builtin_amdgcn_s_barrier();                        // vmcnt NOT drained
        }
    }

    // ---- epilogue: + b2, store f32 ----
    #pragma unroll
    for (int ni = 0; ni < 2; ++ni) {
        const int col = (2 * w + ni) * 32 + l32;
        const float bb = b2[col];
        #pragma unroll
        for (int mi = 0; mi < 2; ++mi) {
            #pragma unroll
            for (int r = 0; r < 16; ++r) {
                const long row = r0 + mi * 32 + (r & 3) + 8 * (r >> 2) + 4 * hi;
                out[row * 256 + col] = acc[mi][ni][r] + bb;
            }
        }
    }
}

extern "C" void kernel_launch(void* const* d_in, const int* in_sizes, int n_in,
                              void* d_out, int out_size, void* d_ws, size_t ws_size,
                              hipStream_t stream) {
    (void)in_sizes; (void)n_in; (void)out_size; (void)ws_size;
    const float* hole  = (const float*)d_in[0];
    const float* board = (const float*)d_in[1];
    const float* W1    = (const float*)d_in[2];
    const float* b1    = (const float*)d_in[3];
    const float* W2    = (const float*)d_in[4];
    const float* b2    = (const float*)d_in[5];
    float* out = (float*)d_out;

    unsigned short* W1F = (unsigned short*)d_ws;            // 131072 bf16 = 256 KB
    unsigned short* W2F = W1F + 131072;                     // 262144 bf16 = 512 KB

    conv_w<<<384, 256, 0, stream>>>(W1, W2, W1F, W2F);
    mlp_fused<<<2048, 256, 0, stream>>>(hole, board, b1, b2, W1F, W2F, out);
}